// Round 4
// baseline (246.734 us; speedup 1.0000x reference)
//
#include <hip/hip_runtime.h>
#include <hip/hip_bf16.h>
#include <stdint.h>
#include <math.h>

typedef __attribute__((ext_vector_type(8))) short bf16x8;
typedef __attribute__((ext_vector_type(4))) float f32x4;

#define TSEQ 4096
#define LOG2E 1.44269504088896340736f
#define SLOPE 0.70710678118654752440f
#define SL2E (SLOPE * LOG2E)
#define NBLK 512

__device__ __forceinline__ unsigned short f32_to_bf16(float f) {
  union { float f; unsigned int u; } v; v.f = f;
  unsigned int r = v.u + 0x7fffu + ((v.u >> 16) & 1u);
  return (unsigned short)(r >> 16);
}

__device__ __forceinline__ unsigned int pk2(float a, float b) {
  union { __hip_bfloat162 h; unsigned int u; } c;
  c.h = __float22bfloat162_rn(make_float2(a, b));  // v_cvt_pk_bf16_f32 on gfx950
  return c.u;
}
__device__ __forceinline__ bf16x8 cvt8(f32x4 a, f32x4 b) {
  union { unsigned int u[4]; bf16x8 v; } r;
  r.u[0] = pk2(a[0], a[1]); r.u[1] = pk2(a[2], a[3]);
  r.u[2] = pk2(b[0], b[1]); r.u[3] = pk2(b[2], b[3]);
  return r.v;
}

// ---- kernel 1: W fp32 -> FRAGMENT-MAJOR bf16 (q pre-scaled 1/32), vt ones, zero barrier ----
// Wb layout: frag(t,nt,s,lane)[j] = W_t[n=nt*16+(lane&15)][k=s*32+(lane>>4)*8+j]
// at offset (((t*4+nt)*32+s)*64+lane)*8  -> proj W loads are lane-contiguous 1KB.
__global__ __launch_bounds__(256) void init_kernel(
    const float* __restrict__ wq, const float* __restrict__ wk,
    const float* __restrict__ wv, unsigned short* __restrict__ Wb,
    unsigned short* __restrict__ vt, unsigned int* __restrict__ cnt) {
  int tid = blockIdx.x * 256 + threadIdx.x;  // 0..131071
  if (tid < 24576) {
    int lane = tid & 63, s = (tid >> 6) & 31, nt = (tid >> 11) & 3, t = tid >> 13;
    int n = nt * 16 + (lane & 15);
    int k = s * 32 + (lane >> 4) * 8;
    const float* src = (t == 0 ? wq : (t == 1 ? wk : wv)) + (size_t)n * 1024 + k;
    f32x4 a = *(const f32x4*)src;
    f32x4 b = *(const f32x4*)(src + 4);
    if (t == 0) {
#pragma unroll
      for (int j = 0; j < 4; ++j) { a[j] *= 0.03125f; b[j] *= 0.03125f; }
    }
    *(bf16x8*)(Wb + (size_t)tid * 8) = cvt8(a, b);
  }
  // vt ones rows (dims 64..79), layout vt[4][80][4096]
  int b2 = tid >> 15, off = (tid & 32767) * 2;
  *(unsigned int*)(vt + (size_t)b2 * 327680 + 262144 + off) = 0x3F803F80u;
  if (tid < 2) cnt[tid] = 0;
}

// device-scope grid barrier: all NBLK blocks co-resident (2/CU guaranteed by resources)
__device__ __forceinline__ void gridbar(unsigned int* c) {
  __syncthreads();  // drains each wave's stores (vmcnt 0) before signaling
  if (threadIdx.x == 0) {
    __threadfence();  // device-scope release
    __hip_atomic_fetch_add(c, 1u, __ATOMIC_RELEASE, __HIP_MEMORY_SCOPE_AGENT);
    while (__hip_atomic_load(c, __ATOMIC_ACQUIRE, __HIP_MEMORY_SCOPE_AGENT) < NBLK)
      __builtin_amdgcn_s_sleep(8);
    __threadfence();  // device-scope acquire
  }
  __syncthreads();
}

// ---- kernel 2: fused proj (barrier-free pipelined) + grid barrier + attn ----
__global__ __launch_bounds__(256, 2) void fused_kernel(
    const float* __restrict__ x, const unsigned short* __restrict__ Wb,
    unsigned short* __restrict__ qb, unsigned short* __restrict__ kb,
    unsigned short* __restrict__ vt, float* __restrict__ out,
    unsigned int* __restrict__ cnt) {
  __shared__ unsigned short pbuf[4][16][88];
  __shared__ float obuf[4][5][16][17];

  const int lane = threadIdx.x & 63;
  const int wave = threadIdx.x >> 6;
  const int l16 = lane & 15, quad = lane >> 4;

  // ================= phase 1: projection (waves 0..2; wave 3 idles) =========
  if (wave < 3) {
    const int t = wave;                 // 0=q 1=k 2=v
    const int r0 = blockIdx.x * 32;     // flat rows [r0, r0+32)
    f32x4 acc[8];
#pragma unroll
    for (int i = 0; i < 8; ++i) acc[i] = (f32x4){0.f, 0.f, 0.f, 0.f};

    const float* xlo = x + (size_t)(r0 + l16) * 1024 + quad * 8;
    const float* xhi = xlo + 16 * 1024;
    const unsigned short* wbase = Wb + (size_t)t * 65536 + lane * 8;

    f32x4 XP[3][4];    // x pipeline, depth 3
    bf16x8 WP[2][4];   // W pipeline, depth 2
#pragma unroll
    for (int p = 0; p < 3; ++p) {
      XP[p][0] = *(const f32x4*)(xlo + p * 32);
      XP[p][1] = *(const f32x4*)(xlo + p * 32 + 4);
      XP[p][2] = *(const f32x4*)(xhi + p * 32);
      XP[p][3] = *(const f32x4*)(xhi + p * 32 + 4);
    }
#pragma unroll
    for (int p = 0; p < 2; ++p)
#pragma unroll
      for (int nt = 0; nt < 4; ++nt)
        WP[p][nt] = *(const bf16x8*)(wbase + nt * 16384 + p * 512);

#pragma unroll
    for (int s = 0; s < 32; ++s) {
      f32x4 a0 = XP[s % 3][0], a1 = XP[s % 3][1];
      f32x4 a2 = XP[s % 3][2], a3 = XP[s % 3][3];
      bf16x8 w0 = WP[s & 1][0], w1 = WP[s & 1][1];
      bf16x8 w2 = WP[s & 1][2], w3 = WP[s & 1][3];
      if (s + 3 < 32) {  // refill x slot (fine-grained vmcnt, no barrier)
        XP[s % 3][0] = *(const f32x4*)(xlo + (s + 3) * 32);
        XP[s % 3][1] = *(const f32x4*)(xlo + (s + 3) * 32 + 4);
        XP[s % 3][2] = *(const f32x4*)(xhi + (s + 3) * 32);
        XP[s % 3][3] = *(const f32x4*)(xhi + (s + 3) * 32 + 4);
      }
      if (s + 2 < 32) {  // refill W slot
#pragma unroll
        for (int nt = 0; nt < 4; ++nt)
          WP[s & 1][nt] = *(const bf16x8*)(wbase + nt * 16384 + (s + 2) * 512);
      }
      bf16x8 alo = cvt8(a0, a1);
      bf16x8 ahi = cvt8(a2, a3);
      acc[0] = __builtin_amdgcn_mfma_f32_16x16x32_bf16(alo, w0, acc[0], 0, 0, 0);
      acc[1] = __builtin_amdgcn_mfma_f32_16x16x32_bf16(alo, w1, acc[1], 0, 0, 0);
      acc[2] = __builtin_amdgcn_mfma_f32_16x16x32_bf16(alo, w2, acc[2], 0, 0, 0);
      acc[3] = __builtin_amdgcn_mfma_f32_16x16x32_bf16(alo, w3, acc[3], 0, 0, 0);
      acc[4] = __builtin_amdgcn_mfma_f32_16x16x32_bf16(ahi, w0, acc[4], 0, 0, 0);
      acc[5] = __builtin_amdgcn_mfma_f32_16x16x32_bf16(ahi, w1, acc[5], 0, 0, 0);
      acc[6] = __builtin_amdgcn_mfma_f32_16x16x32_bf16(ahi, w2, acc[6], 0, 0, 0);
      acc[7] = __builtin_amdgcn_mfma_f32_16x16x32_bf16(ahi, w3, acc[7], 0, 0, 0);
    }

    // epilogue: C/D col=l16, row=quad*4+r
#pragma unroll
    for (int rt = 0; rt < 2; ++rt) {
#pragma unroll
      for (int nt = 0; nt < 4; ++nt) {
#pragma unroll
        for (int r = 0; r < 4; ++r) {
          int row = r0 + rt * 16 + quad * 4 + r;
          unsigned short hv = f32_to_bf16(acc[rt * 4 + nt][r]);
          if (t == 0) {
            qb[(size_t)row * 64 + nt * 16 + l16] = hv;
          } else if (t == 1) {
            kb[(size_t)row * 64 + nt * 16 + l16] = hv;
          } else {
            int b = row >> 12, tt = row & 4095;
            vt[((size_t)b * 80 + nt * 16 + l16) * TSEQ + tt] = hv;
          }
        }
      }
    }
  }

  // ================= grid barrier ===========================================
  gridbar(cnt);

  // ================= phase 2: windowed causal attention =====================
  // wave = (q-tile qi, key-half h); analytic shift slope*row; l via ones rows.
  {
    const int qi = wave >> 1;
    const int h = wave & 1;
    const int tid = blockIdx.x * 2 + qi;  // 0..1023
    const int b = tid & 3;
    const int r0 = (tid >> 2) << 4;
    const int j0 = (r0 > 112) ? (r0 - 112) : 0;
    const int jb = j0 + h * 64;

    const unsigned short* kbase = kb + (size_t)b * TSEQ * 64;
    const unsigned short* vbase = vt + (size_t)b * 80 * TSEQ;

    const unsigned short* qrow = qb + (size_t)(b * TSEQ + r0 + l16) * 64 + quad * 8;
    bf16x8 qa0 = *(const bf16x8*)qrow;
    bf16x8 qa1 = *(const bf16x8*)(qrow + 32);

    f32x4 o[5];
#pragma unroll
    for (int dt = 0; dt < 5; ++dt) o[dt] = (f32x4){0.f, 0.f, 0.f, 0.f};

    const int irel = jb + l16 - r0 - quad * 4;  // j - row at nt=0,r=0
    const float fb = SL2E * (float)irel;
    const bool needmask = (h == 1) || (r0 < 64);

#pragma unroll
    for (int nt = 0; nt < 4; ++nt) {
      const unsigned short* krow = kbase + (size_t)(jb + nt * 16 + l16) * 64 + quad * 8;
      f32x4 sa = (f32x4){0.f, 0.f, 0.f, 0.f};
      sa = __builtin_amdgcn_mfma_f32_16x16x32_bf16(qa0, *(const bf16x8*)krow, sa, 0, 0, 0);
      sa = __builtin_amdgcn_mfma_f32_16x16x32_bf16(qa1, *(const bf16x8*)(krow + 32), sa, 0, 0, 0);
      const int koff = nt * 16;
#pragma unroll
      for (int r = 0; r < 4; ++r) {
        float arg = fmaf(sa[r], LOG2E, fb + SL2E * (float)(koff - r));
        float p = exp2f(arg);
        if (needmask && (irel + koff - r > 0)) p = 0.f;  // causal
        pbuf[wave][quad * 4 + r][nt * 16 + l16] = f32_to_bf16(p);
      }
    }
    // same-wave DS write->read is in-order (validated R1-R3)
    bf16x8 pa0 = *(const bf16x8*)&pbuf[wave][l16][quad * 8];
    bf16x8 pa1 = *(const bf16x8*)&pbuf[wave][l16][32 + quad * 8];

#pragma unroll
    for (int dt = 0; dt < 5; ++dt) {  // dt=4: ones rows -> l = sum(p)
      const unsigned short* vrow = vbase + (size_t)(dt * 16 + l16) * TSEQ + jb + quad * 8;
      o[dt] = __builtin_amdgcn_mfma_f32_16x16x32_bf16(pa0, *(const bf16x8*)vrow, o[dt], 0, 0, 0);
      o[dt] = __builtin_amdgcn_mfma_f32_16x16x32_bf16(pa1, *(const bf16x8*)(vrow + 32), o[dt], 0, 0, 0);
    }

#pragma unroll
    for (int dt = 0; dt < 5; ++dt)
#pragma unroll
      for (int r = 0; r < 4; ++r)
        obuf[wave][dt][quad * 4 + r][l16] = o[dt][r];
  }

  __syncthreads();

  // combine halves: 2048 outputs, 8 per thread
  {
    const int qt = threadIdx.x >> 7;
    const int rr = (threadIdx.x >> 3) & 15;
    const int c0 = (threadIdx.x & 7) * 8;
    const int tid2 = blockIdx.x * 2 + qt;
    const int b2 = tid2 & 3;
    const int r02 = (tid2 >> 2) << 4;
    float l = obuf[qt * 2][4][rr][0] + obuf[qt * 2 + 1][4][rr][0];
    float invl = 1.0f / l;
    float res[8];
#pragma unroll
    for (int i = 0; i < 8; ++i) {
      int c = c0 + i;
      res[i] = (obuf[qt * 2][c >> 4][rr][c & 15] + obuf[qt * 2 + 1][c >> 4][rr][c & 15]) * invl;
    }
    float* ob = out + (size_t)(b2 * TSEQ + r02 + rr) * 64 + c0;
    *(f32x4*)ob = (f32x4){res[0], res[1], res[2], res[3]};
    *(f32x4*)(ob + 4) = (f32x4){res[4], res[5], res[6], res[7]};
  }
}

extern "C" void kernel_launch(void* const* d_in, const int* in_sizes, int n_in,
                              void* d_out, int out_size, void* d_ws, size_t ws_size,
                              hipStream_t stream) {
  const float* x  = (const float*)d_in[0];
  const float* wq = (const float*)d_in[1];
  const float* wk = (const float*)d_in[2];
  const float* wv = (const float*)d_in[3];
  float* out = (float*)d_out;

  // ws: Wb 384K | qb 2M | kb 2M | vt 2.62M ; barrier counters at ws tail (64B-aligned)
  char* ws = (char*)d_ws;
  unsigned short* Wb = (unsigned short*)(ws);
  unsigned short* qb = (unsigned short*)(ws + 393216);
  unsigned short* kb = (unsigned short*)(ws + 393216 + 2097152);
  unsigned short* vt = (unsigned short*)(ws + 393216 + 2 * 2097152);
  unsigned int* cnt = (unsigned int*)(ws + ((ws_size - 64) & ~(size_t)63));

  init_kernel<<<NBLK, 256, 0, stream>>>(wq, wk, wv, Wb, vt, cnt);
  fused_kernel<<<NBLK, 256, 0, stream>>>(x, Wb, qb, kb, vt, out, cnt);
}

// Round 5
// 143.951 us; speedup vs baseline: 1.7140x; 1.7140x over previous
//
#include <hip/hip_runtime.h>
#include <hip/hip_bf16.h>
#include <stdint.h>
#include <math.h>

typedef __attribute__((ext_vector_type(8))) short bf16x8;
typedef __attribute__((ext_vector_type(4))) float f32x4;

#define TSEQ 4096
#define LOG2E 1.44269504088896340736f
#define SLOPE 0.70710678118654752440f
#define SL2E (SLOPE * LOG2E)

__device__ __forceinline__ unsigned short f32_to_bf16(float f) {
  union { float f; unsigned int u; } v; v.f = f;
  unsigned int r = v.u + 0x7fffu + ((v.u >> 16) & 1u);
  return (unsigned short)(r >> 16);
}

__device__ __forceinline__ unsigned int pk2(float a, float b) {
  union { __hip_bfloat162 h; unsigned int u; } c;
  c.h = __float22bfloat162_rn(make_float2(a, b));  // v_cvt_pk_bf16_f32
  return c.u;
}
__device__ __forceinline__ bf16x8 cvt8(f32x4 a, f32x4 b) {
  union { unsigned int u[4]; bf16x8 v; } r;
  r.u[0] = pk2(a[0], a[1]); r.u[1] = pk2(a[2], a[3]);
  r.u[2] = pk2(b[0], b[1]); r.u[3] = pk2(b[2], b[3]);
  return r.v;
}

// ---- kernel 1: W fp32 -> FRAGMENT-MAJOR bf16 (q pre-scaled 1/32) + vt ones ----
// Wb frag(ci,s,lane)[j] = W[n=(ci&3)*16+(lane&15)][k=s*32+(lane>>4)*8+j],
// ci = coltile 0..11 (q:0-3,k:4-7,v:8-11), at offset ((ci*32+s)*64+lane)*8.
__global__ __launch_bounds__(256) void init_kernel(
    const float* __restrict__ wq, const float* __restrict__ wk,
    const float* __restrict__ wv, unsigned short* __restrict__ Wb,
    unsigned short* __restrict__ vt) {
  int tid = blockIdx.x * 256 + threadIdx.x;  // 0..131071
  if (tid < 24576) {
    int lane = tid & 63, s = (tid >> 6) & 31, nt = (tid >> 11) & 3, t = tid >> 13;
    int n = nt * 16 + (lane & 15);
    int k = s * 32 + (lane >> 4) * 8;
    const float* src = (t == 0 ? wq : (t == 1 ? wk : wv)) + (size_t)n * 1024 + k;
    f32x4 a = *(const f32x4*)src;
    f32x4 b = *(const f32x4*)(src + 4);
    if (t == 0) {
#pragma unroll
      for (int j = 0; j < 4; ++j) { a[j] *= 0.03125f; b[j] *= 0.03125f; }
    }
    *(bf16x8*)(Wb + (size_t)tid * 8) = cvt8(a, b);
  }
  // vt ones rows (dims 64..79), vt layout [4][80][4096]
  int b2 = tid >> 15, off = (tid & 32767) * 2;
  *(unsigned int*)(vt + (size_t)b2 * 327680 + 262144 + off) = 0x3F803F80u;
}

// ---- kernel 2: qkv projection, 4096 waves (16/CU), no LDS, no barriers -------
// Block = 16 rows; wave = 16 rows x 3 coltiles; K=1024 in 32 MFMA steps.
// 1-deep explicit prefetch; tiny VGPR footprint so compiler keeps loads early.
__global__ __launch_bounds__(256, 4) void proj_kernel(
    const float* __restrict__ x, const unsigned short* __restrict__ Wb,
    unsigned short* __restrict__ qb, unsigned short* __restrict__ kb,
    unsigned short* __restrict__ vt) {
  const int lane = threadIdx.x & 63;
  const int wave = threadIdx.x >> 6;
  const int l16 = lane & 15, quad = lane >> 4;
  const int r0 = blockIdx.x * 16;
  const int ci0 = wave * 3;

  f32x4 acc0 = (f32x4){0.f, 0.f, 0.f, 0.f};
  f32x4 acc1 = acc0, acc2 = acc0;

  const float* xa = x + (size_t)(r0 + l16) * 1024 + quad * 8;
  const unsigned short* wl = Wb + (size_t)ci0 * 16384 + lane * 8;

  f32x4 xA = *(const f32x4*)xa;
  f32x4 xB = *(const f32x4*)(xa + 4);
  bf16x8 w0 = *(const bf16x8*)(wl);
  bf16x8 w1 = *(const bf16x8*)(wl + 16384);
  bf16x8 w2 = *(const bf16x8*)(wl + 32768);

#pragma unroll 2
  for (int s = 0; s < 32; ++s) {
    f32x4 cA = xA, cB = xB;
    bf16x8 c0 = w0, c1 = w1, c2 = w2;
    if (s < 31) {  // prefetch next step before current compute
      const float* xn = xa + (s + 1) * 32;
      xA = *(const f32x4*)xn;
      xB = *(const f32x4*)(xn + 4);
      const unsigned short* wn = wl + (s + 1) * 512;
      w0 = *(const bf16x8*)(wn);
      w1 = *(const bf16x8*)(wn + 16384);
      w2 = *(const bf16x8*)(wn + 32768);
    }
    bf16x8 af = cvt8(cA, cB);
    acc0 = __builtin_amdgcn_mfma_f32_16x16x32_bf16(af, c0, acc0, 0, 0, 0);
    acc1 = __builtin_amdgcn_mfma_f32_16x16x32_bf16(af, c1, acc1, 0, 0, 0);
    acc2 = __builtin_amdgcn_mfma_f32_16x16x32_bf16(af, c2, acc2, 0, 0, 0);
  }

  // epilogue: C/D col=l16, row=quad*4+r
  f32x4 av[3] = {acc0, acc1, acc2};
#pragma unroll
  for (int j = 0; j < 3; ++j) {
    const int ci = ci0 + j;
#pragma unroll
    for (int r = 0; r < 4; ++r) {
      int row = r0 + quad * 4 + r;
      unsigned short hv = f32_to_bf16(av[j][r]);
      if (ci < 4) {
        qb[(size_t)row * 64 + ci * 16 + l16] = hv;
      } else if (ci < 8) {
        kb[(size_t)row * 64 + (ci - 4) * 16 + l16] = hv;
      } else {
        int b = row >> 12, tt = row & 4095;
        vt[((size_t)b * 80 + (ci - 8) * 16 + l16) * TSEQ + tt] = hv;
      }
    }
  }
}

// ---- kernel 3: windowed causal attention, 4 waves per q-tile (32 keys each) ---
// Analytic shift slope*row => partials linear: O = sum O_h, l = sum l_h.
// 1024 blocks x 4 waves = 16 waves/CU; combine via LDS.
__global__ __launch_bounds__(256, 4) void attn_kernel(
    const unsigned short* __restrict__ qb, const unsigned short* __restrict__ kb,
    const unsigned short* __restrict__ vt, float* __restrict__ out) {
  __shared__ unsigned short pbuf[4][16][40];  // 16 q x 32 keys (+pad), 80B stride
  __shared__ float obuf[4][5][16][17];        // partial O (+l in [4])

  const int lane = threadIdx.x & 63;
  const int wave = threadIdx.x >> 6;  // key-quarter h
  const int l16 = lane & 15, quad = lane >> 4;
  const int tid = blockIdx.x;  // q-tile 0..1023
  const int b = tid & 3;
  const int r0 = (tid >> 2) << 4;
  const int j0 = (r0 > 112) ? (r0 - 112) : 0;
  const int jb = j0 + wave * 32;

  const unsigned short* kbase = kb + (size_t)b * TSEQ * 64;
  const unsigned short* vbase = vt + (size_t)b * 80 * TSEQ;

  const unsigned short* qrow = qb + (size_t)(b * TSEQ + r0 + l16) * 64 + quad * 8;
  bf16x8 qa0 = *(const bf16x8*)qrow;
  bf16x8 qa1 = *(const bf16x8*)(qrow + 32);

  f32x4 o[5];
#pragma unroll
  for (int dt = 0; dt < 5; ++dt) o[dt] = (f32x4){0.f, 0.f, 0.f, 0.f};

  const int irel = jb + l16 - r0 - quad * 4;  // key - query at nt=0,r=0
  const float fb = SL2E * (float)irel;

#pragma unroll
  for (int nt = 0; nt < 2; ++nt) {
    const unsigned short* krow = kbase + (size_t)(jb + nt * 16 + l16) * 64 + quad * 8;
    f32x4 sa = (f32x4){0.f, 0.f, 0.f, 0.f};
    sa = __builtin_amdgcn_mfma_f32_16x16x32_bf16(qa0, *(const bf16x8*)krow, sa, 0, 0, 0);
    sa = __builtin_amdgcn_mfma_f32_16x16x32_bf16(qa1, *(const bf16x8*)(krow + 32), sa, 0, 0, 0);
#pragma unroll
    for (int r = 0; r < 4; ++r) {
      float arg = fmaf(sa[r], LOG2E, fb + SL2E * (float)(nt * 16 - r));
      float p = exp2f(arg);
      if (irel + nt * 16 - r > 0) p = 0.f;  // causal
      pbuf[wave][quad * 4 + r][nt * 16 + l16] = f32_to_bf16(p);
    }
  }
  // same-wave DS write->read is in-order (validated R1-R4)
  bf16x8 pa = *(const bf16x8*)&pbuf[wave][l16][quad * 8];

#pragma unroll
  for (int dt = 0; dt < 5; ++dt) {  // dt=4: ones rows -> l = sum(p)
    const unsigned short* vrow = vbase + (size_t)(dt * 16 + l16) * TSEQ + jb + quad * 8;
    o[dt] = __builtin_amdgcn_mfma_f32_16x16x32_bf16(pa, *(const bf16x8*)vrow, o[dt], 0, 0, 0);
  }

#pragma unroll
  for (int dt = 0; dt < 5; ++dt)
#pragma unroll
    for (int r = 0; r < 4; ++r)
      obuf[wave][dt][quad * 4 + r][l16] = o[dt][r];

  __syncthreads();

  // combine 4 quarters: 16 rows x 64 cols, 4 floats/thread
  const int rr = threadIdx.x >> 4;
  const int c0 = (threadIdx.x & 15) * 4;
  const int dt = c0 >> 4, cc = c0 & 15;
  float l = obuf[0][4][rr][0] + obuf[1][4][rr][0] + obuf[2][4][rr][0] + obuf[3][4][rr][0];
  float invl = 1.0f / l;
  f32x4 res;
#pragma unroll
  for (int i = 0; i < 4; ++i)
    res[i] = (obuf[0][dt][rr][cc + i] + obuf[1][dt][rr][cc + i] +
              obuf[2][dt][rr][cc + i] + obuf[3][dt][rr][cc + i]) * invl;
  *(f32x4*)(out + (size_t)(b * TSEQ + r0 + rr) * 64 + c0) = res;
}

extern "C" void kernel_launch(void* const* d_in, const int* in_sizes, int n_in,
                              void* d_out, int out_size, void* d_ws, size_t ws_size,
                              hipStream_t stream) {
  const float* x  = (const float*)d_in[0];
  const float* wq = (const float*)d_in[1];
  const float* wk = (const float*)d_in[2];
  const float* wv = (const float*)d_in[3];
  float* out = (float*)d_out;

  // ws: Wb 384K | qb 2M | kb 2M | vt 2.62M (80 rows: 64 V + 16 ones)
  char* ws = (char*)d_ws;
  unsigned short* Wb = (unsigned short*)(ws);
  unsigned short* qb = (unsigned short*)(ws + 393216);
  unsigned short* kb = (unsigned short*)(ws + 393216 + 2097152);
  unsigned short* vt = (unsigned short*)(ws + 393216 + 2 * 2097152);

  init_kernel<<<512, 256, 0, stream>>>(wq, wk, wv, Wb, vt);
  proj_kernel<<<1024, 256, 0, stream>>>(x, Wb, qb, kb, vt);
  attn_kernel<<<1024, 256, 0, stream>>>(qb, kb, vt, out);
}

// Round 6
// 124.418 us; speedup vs baseline: 1.9831x; 1.1570x over previous
//
#include <hip/hip_runtime.h>
#include <hip/hip_bf16.h>
#include <stdint.h>
#include <math.h>

typedef __attribute__((ext_vector_type(8))) short bf16x8;
typedef __attribute__((ext_vector_type(4))) float f32x4;

#define TSEQ 4096
#define LOG2E 1.44269504088896340736f
#define SLOPE 0.70710678118654752440f
#define SL2E (SLOPE * LOG2E)

__device__ __forceinline__ unsigned short f32_to_bf16(float f) {
  union { float f; unsigned int u; } v; v.f = f;
  unsigned int r = v.u + 0x7fffu + ((v.u >> 16) & 1u);
  return (unsigned short)(r >> 16);
}

__device__ __forceinline__ unsigned int pk2(float a, float b) {
  union { __hip_bfloat162 h; unsigned int u; } c;
  c.h = __float22bfloat162_rn(make_float2(a, b));  // v_cvt_pk_bf16_f32
  return c.u;
}
__device__ __forceinline__ bf16x8 cvt8(f32x4 a, f32x4 b) {
  union { unsigned int u[4]; bf16x8 v; } r;
  r.u[0] = pk2(a[0], a[1]); r.u[1] = pk2(a[2], a[3]);
  r.u[2] = pk2(b[0], b[1]); r.u[3] = pk2(b[2], b[3]);
  return r.v;
}

// async global->LDS, 16B/lane; dest = wave-uniform base + lane*16 (verified R3)
__device__ __forceinline__ void async_cp16(const void* g, void* l) {
  __builtin_amdgcn_global_load_lds(
      (const __attribute__((address_space(1))) unsigned int*)g,
      (__attribute__((address_space(3))) unsigned int*)l, 16, 0, 0);
}

// ---- kernel 1: W fp32 -> FRAGMENT-MAJOR bf16 (q pre-scaled 1/32) + vt ones ----
// Wb frag(ci,s,lane)[j] = W[n=(ci&3)*16+(lane&15)][k=s*32+(lane>>4)*8+j],
// ci = coltile 0..11 (q:0-3,k:4-7,v:8-11), at offset ((ci*32+s)*64+lane)*8.
__global__ __launch_bounds__(256) void init_kernel(
    const float* __restrict__ wq, const float* __restrict__ wk,
    const float* __restrict__ wv, unsigned short* __restrict__ Wb,
    unsigned short* __restrict__ vt) {
  int tid = blockIdx.x * 256 + threadIdx.x;  // 0..131071
  if (tid < 24576) {
    int lane = tid & 63, s = (tid >> 6) & 31, nt = (tid >> 11) & 3, t = tid >> 13;
    int n = nt * 16 + (lane & 15);
    int k = s * 32 + (lane >> 4) * 8;
    const float* src = (t == 0 ? wq : (t == 1 ? wk : wv)) + (size_t)n * 1024 + k;
    f32x4 a = *(const f32x4*)src;
    f32x4 b = *(const f32x4*)(src + 4);
    if (t == 0) {
#pragma unroll
      for (int j = 0; j < 4; ++j) { a[j] *= 0.03125f; b[j] *= 0.03125f; }
    }
    *(bf16x8*)(Wb + (size_t)tid * 8) = cvt8(a, b);
  }
  // vt ones rows (dims 64..79), vt layout [4][80][4096]
  int b2 = tid >> 15, off = (tid & 32767) * 2;
  *(unsigned int*)(vt + (size_t)b2 * 327680 + 262144 + off) = 0x3F803F80u;
}

// ---- kernel 2: qkv projection, all inputs via async global->LDS DMA ----------
// 512 blocks x 256 thr; block = 32 rows x 192 cols; 16 steps of K=64.
// Per step per wave: 8 async copies (x:2, W:6) -> 1 barrier drain (not 160
// serial load latencies). Wave = 32 rows x 3 coltiles.
__global__ __launch_bounds__(256, 2) void proj_kernel(
    const float* __restrict__ x, const unsigned short* __restrict__ Wb,
    unsigned short* __restrict__ qb, unsigned short* __restrict__ kb,
    unsigned short* __restrict__ vt) {
  __shared__ float xbuf[32][64];                 // 8 KB; slot p of row r = chunk p^(r&15)
  __shared__ unsigned short wbuf[12][2][64][8];  // 24 KB; frag-major, lane*16B

  const int lane = threadIdx.x & 63;
  const int wave = threadIdx.x >> 6;
  const int l16 = lane & 15, quad = lane >> 4;
  const int R0 = blockIdx.x * 32;
  const int ci0 = wave * 3;

  f32x4 acc[2][3];
#pragma unroll
  for (int st = 0; st < 2; ++st)
#pragma unroll
    for (int j = 0; j < 3; ++j) acc[st][j] = (f32x4){0.f, 0.f, 0.f, 0.f};

  // x staging: wave stages rows wave*8 .. wave*8+7 (two 4-row chunks), XOR-swizzled
  const int rA = wave * 8 + quad;
  const int rB = rA + 4;
  const int gA = l16 ^ (rA & 15);
  const int gB = l16 ^ (rB & 15);
  const float* srcA = x + (size_t)(R0 + rA) * 1024 + gA * 4;
  const float* srcB = x + (size_t)(R0 + rB) * 1024 + gB * 4;
  float* dstA = &xbuf[wave * 8][0];
  float* dstB = &xbuf[wave * 8 + 4][0];

  for (int step = 0; step < 16; ++step) {
    const int k0 = step * 64;
    async_cp16(srcA + k0, dstA);
    async_cp16(srcB + k0, dstB);
#pragma unroll
    for (int j = 0; j < 3; ++j) {
      const unsigned short* wsrc = Wb + ((size_t)((ci0 + j) * 32 + step * 2) * 64 + lane) * 8;
      async_cp16(wsrc, &wbuf[ci0 + j][0][0][0]);
      async_cp16(wsrc + 512, &wbuf[ci0 + j][1][0][0]);
    }
    __syncthreads();  // drain all copies (vmcnt 0) + tile ready

#pragma unroll
    for (int ss = 0; ss < 2; ++ss) {
      bf16x8 af[2];
#pragma unroll
      for (int st = 0; st < 2; ++st) {
        const float* base = &xbuf[st * 16 + l16][0];
        f32x4 a0 = *(const f32x4*)(base + ((ss * 8 + quad * 2) ^ l16) * 4);
        f32x4 a1 = *(const f32x4*)(base + ((ss * 8 + quad * 2 + 1) ^ l16) * 4);
        af[st] = cvt8(a0, a1);
      }
#pragma unroll
      for (int j = 0; j < 3; ++j) {
        bf16x8 wfr = *(const bf16x8*)&wbuf[ci0 + j][ss][lane][0];
        acc[0][j] = __builtin_amdgcn_mfma_f32_16x16x32_bf16(af[0], wfr, acc[0][j], 0, 0, 0);
        acc[1][j] = __builtin_amdgcn_mfma_f32_16x16x32_bf16(af[1], wfr, acc[1][j], 0, 0, 0);
      }
    }
    __syncthreads();  // protect tiles before next overwrite
  }

  // epilogue: C/D col=l16, row=quad*4+r
#pragma unroll
  for (int st = 0; st < 2; ++st) {
#pragma unroll
    for (int j = 0; j < 3; ++j) {
      const int ci = ci0 + j;
#pragma unroll
      for (int r = 0; r < 4; ++r) {
        int row = R0 + st * 16 + quad * 4 + r;
        unsigned short hv = f32_to_bf16(acc[st][j][r]);
        if (ci < 4) {
          qb[(size_t)row * 64 + ci * 16 + l16] = hv;
        } else if (ci < 8) {
          kb[(size_t)row * 64 + (ci - 4) * 16 + l16] = hv;
        } else {
          int b = row >> 12, tt = row & 4095;
          vt[((size_t)b * 80 + (ci - 8) * 16 + l16) * TSEQ + tt] = hv;
        }
      }
    }
  }
}

// ---- kernel 3: windowed causal attention, 4 waves per q-tile (32 keys each) ---
// Analytic shift slope*row => partials linear: O = sum O_h, l = sum l_h.
__global__ __launch_bounds__(256, 4) void attn_kernel(
    const unsigned short* __restrict__ qb, const unsigned short* __restrict__ kb,
    const unsigned short* __restrict__ vt, float* __restrict__ out) {
  __shared__ unsigned short pbuf[4][16][40];  // 16 q x 32 keys (+pad)
  __shared__ float obuf[4][5][16][17];        // partial O (+l in [4])

  const int lane = threadIdx.x & 63;
  const int wave = threadIdx.x >> 6;  // key-quarter
  const int l16 = lane & 15, quad = lane >> 4;
  const int tid = blockIdx.x;  // q-tile 0..1023
  const int b = tid & 3;
  const int r0 = (tid >> 2) << 4;
  const int j0 = (r0 > 112) ? (r0 - 112) : 0;
  const int jb = j0 + wave * 32;

  const unsigned short* kbase = kb + (size_t)b * TSEQ * 64;
  const unsigned short* vbase = vt + (size_t)b * 80 * TSEQ;

  const unsigned short* qrow = qb + (size_t)(b * TSEQ + r0 + l16) * 64 + quad * 8;
  bf16x8 qa0 = *(const bf16x8*)qrow;
  bf16x8 qa1 = *(const bf16x8*)(qrow + 32);

  f32x4 o[5];
#pragma unroll
  for (int dt = 0; dt < 5; ++dt) o[dt] = (f32x4){0.f, 0.f, 0.f, 0.f};

  const int irel = jb + l16 - r0 - quad * 4;  // key - query at nt=0,r=0
  const float fb = SL2E * (float)irel;

#pragma unroll
  for (int nt = 0; nt < 2; ++nt) {
    const unsigned short* krow = kbase + (size_t)(jb + nt * 16 + l16) * 64 + quad * 8;
    f32x4 sa = (f32x4){0.f, 0.f, 0.f, 0.f};
    sa = __builtin_amdgcn_mfma_f32_16x16x32_bf16(qa0, *(const bf16x8*)krow, sa, 0, 0, 0);
    sa = __builtin_amdgcn_mfma_f32_16x16x32_bf16(qa1, *(const bf16x8*)(krow + 32), sa, 0, 0, 0);
#pragma unroll
    for (int r = 0; r < 4; ++r) {
      float arg = fmaf(sa[r], LOG2E, fb + SL2E * (float)(nt * 16 - r));
      float p = exp2f(arg);
      if (irel + nt * 16 - r > 0) p = 0.f;  // causal
      pbuf[wave][quad * 4 + r][nt * 16 + l16] = f32_to_bf16(p);
    }
  }
  // same-wave DS write->read is in-order (validated R1-R5)
  bf16x8 pa = *(const bf16x8*)&pbuf[wave][l16][quad * 8];

#pragma unroll
  for (int dt = 0; dt < 5; ++dt) {  // dt=4: ones rows -> l = sum(p)
    const unsigned short* vrow = vbase + (size_t)(dt * 16 + l16) * TSEQ + jb + quad * 8;
    o[dt] = __builtin_amdgcn_mfma_f32_16x16x32_bf16(pa, *(const bf16x8*)vrow, o[dt], 0, 0, 0);
  }

#pragma unroll
  for (int dt = 0; dt < 5; ++dt)
#pragma unroll
    for (int r = 0; r < 4; ++r)
      obuf[wave][dt][quad * 4 + r][l16] = o[dt][r];

  __syncthreads();

  // combine 4 quarters: 16 rows x 64 cols, 4 floats/thread
  const int rr = threadIdx.x >> 4;
  const int c0 = (threadIdx.x & 15) * 4;
  const int dt = c0 >> 4, cc = c0 & 15;
  float l = obuf[0][4][rr][0] + obuf[1][4][rr][0] + obuf[2][4][rr][0] + obuf[3][4][rr][0];
  float invl = 1.0f / l;
  f32x4 res;
#pragma unroll
  for (int i = 0; i < 4; ++i)
    res[i] = (obuf[0][dt][rr][cc + i] + obuf[1][dt][rr][cc + i] +
              obuf[2][dt][rr][cc + i] + obuf[3][dt][rr][cc + i]) * invl;
  *(f32x4*)(out + (size_t)(b * TSEQ + r0 + rr) * 64 + c0) = res;
}

extern "C" void kernel_launch(void* const* d_in, const int* in_sizes, int n_in,
                              void* d_out, int out_size, void* d_ws, size_t ws_size,
                              hipStream_t stream) {
  const float* x  = (const float*)d_in[0];
  const float* wq = (const float*)d_in[1];
  const float* wk = (const float*)d_in[2];
  const float* wv = (const float*)d_in[3];
  float* out = (float*)d_out;

  // ws: Wb 384K | qb 2M | kb 2M | vt 2.62M (80 rows: 64 V + 16 ones)
  char* ws = (char*)d_ws;
  unsigned short* Wb = (unsigned short*)(ws);
  unsigned short* qb = (unsigned short*)(ws + 393216);
  unsigned short* kb = (unsigned short*)(ws + 393216 + 2097152);
  unsigned short* vt = (unsigned short*)(ws + 393216 + 2 * 2097152);

  init_kernel<<<512, 256, 0, stream>>>(wq, wk, wv, Wb, vt);
  proj_kernel<<<512, 256, 0, stream>>>(x, Wb, qb, kb, vt);
  attn_kernel<<<1024, 256, 0, stream>>>(qb, kb, vt, out);
}